// Round 1
// 523.920 us; speedup vs baseline: 1.0911x; 1.0911x over previous
//
#include <hip/hip_runtime.h>

// JKNet (6-layer GCN + JK concat) on MI355X — R8:
//   * single fused prep kernel: all 6 weight transposes (fp32->bf16, c-major)
//     + degi zeroing in one launch (was 7 launches)
//   * agg_csr: 4-deep gather pipeline per half-wave (8 outstanding gathers/wave),
//     batched col loads, dual accumulators to break FP dependency chains
//   * all 5 JK layers kept as bf16 segments (hball) so gemm_out reads 48MB bf16
//     instead of 96MB fp32 (runtime fallback to fp32 path if ws too small)
// Layout facts (learn_hip m89): A[m=lane&15][k=quad*8+j], B[k][n=lane&15] (k=quad*8+j),
// D: col=lane&15, row=quad*4+reg.

typedef unsigned short ushortT;
typedef __attribute__((ext_vector_type(8))) short bf16x8;
typedef __attribute__((ext_vector_type(4))) float f32x4;

__device__ __forceinline__ ushortT f2b(float f) {
    union { float f; unsigned int u; } v;
    v.f = f;
    unsigned int lsb = (v.u >> 16) & 1u;
    v.u += 0x7fffu + lsb;  // RNE
    return (ushortT)(v.u >> 16);
}
__device__ __forceinline__ float b2f(ushortT u) {
    union { float f; unsigned int u; } v;
    v.u = ((unsigned int)u) << 16;
    return v.f;
}

// ---- fused prep: transpose+convert all weights, zero degi -----------------
// region [0, 5*9216): W1 + Ws[0..3]  (96x96 each, Wt[c*96+k] = W[k*96+c])
// region [5*9216, +30720): Wout (480x64, Wt[c*480+k] = W[k*64+c])
// region [76800, +n): degi = 0
__global__ void prep_kernel(const float* __restrict__ W1, const float* __restrict__ Wsl,
                            const float* __restrict__ Wout, ushortT* __restrict__ wt1,
                            ushortT* __restrict__ wts, ushortT* __restrict__ wto,
                            int* __restrict__ degi, int n) {
    const int SQ = 96 * 96;        // 9216
    const int T1 = 5 * SQ;         // 46080
    const int T2 = T1 + 480 * 64;  // 76800
    int i = blockIdx.x * blockDim.x + threadIdx.x;
    if (i < T1) {
        int l = i / SQ, j = i - l * SQ;
        int c = j / 96, k = j - c * 96;
        if (l == 0)
            wt1[j] = f2b(W1[k * 96 + c]);
        else
            wts[(size_t)(l - 1) * SQ + j] = f2b(Wsl[(size_t)(l - 1) * SQ + k * 96 + c]);
    } else if (i < T2) {
        int j = i - T1;
        int c = j / 480, k = j - c * 480;
        wto[j] = f2b(Wout[(size_t)k * 64 + c]);
    } else {
        int j = i - T2;
        if (j < n) degi[j] = 0;
    }
}

// ---- CSR build -------------------------------------------------------------
__global__ void count_kernel(const int* __restrict__ dst, int* __restrict__ degi, int E) {
    int e = blockIdx.x * blockDim.x + threadIdx.x;
    if (e < E) atomicAdd(&degi[dst[e]], 1);
}

__global__ void scan1(const int* __restrict__ degi, int* __restrict__ row_start,
                      int* __restrict__ partials, int n) {
    __shared__ int tmp[256];
    const int t = threadIdx.x;
    const int i = blockIdx.x * 256 + t;
    int val = (i < n) ? degi[i] : 0;
    tmp[t] = val;
    __syncthreads();
    for (int off = 1; off < 256; off <<= 1) {
        int v = (t >= off) ? tmp[t - off] : 0;
        __syncthreads();
        tmp[t] += v;
        __syncthreads();
    }
    if (i < n) row_start[i] = tmp[t] - val;
    if (t == 255) partials[blockIdx.x] = tmp[255];
}

__global__ void scan2(int* __restrict__ partials, int nb) {
    __shared__ int tmp[256];
    const int t = threadIdx.x;
    int val = (t < nb) ? partials[t] : 0;
    tmp[t] = val;
    __syncthreads();
    for (int off = 1; off < 256; off <<= 1) {
        int v = (t >= off) ? tmp[t - off] : 0;
        __syncthreads();
        tmp[t] += v;
        __syncthreads();
    }
    if (t < nb) partials[t] = tmp[t] - val;
}

__global__ void scan3(const int* __restrict__ degi, int* __restrict__ row_start,
                      const int* __restrict__ partials, float* __restrict__ dinv,
                      int n, int E) {
    const int i = blockIdx.x * 256 + threadIdx.x;
    if (i < n) {
        row_start[i] += partials[blockIdx.x];
        dinv[i] = rsqrtf((float)degi[i] + 1.0f);
    }
    if (i == 0) row_start[n] = E;
}

__global__ void fill_kernel(const int* __restrict__ src, const int* __restrict__ dst,
                            const int* __restrict__ row_start, int* __restrict__ degi,
                            int* __restrict__ col, int E) {
    int e = blockIdx.x * blockDim.x + threadIdx.x;
    if (e < E) {
        int d = dst[e];
        int pos = row_start[d] + atomicSub(&degi[d], 1) - 1;
        col[pos] = src[e];
    }
}

// ---- MFMA GEMM [n,96]x[96,96] -> g(bf16) = (X@W)*dinv[row] -----------------
// 64 rows/block, 256 thr = 4 waves, wave = 16-row strip x 96 cols (6 mfma accs).
template <typename TIN>
__global__ __launch_bounds__(256) void gemm96_mfma(const TIN* __restrict__ X,
                                                   const ushortT* __restrict__ Wt, // [96][96] c-major
                                                   const float* __restrict__ dinv,
                                                   ushortT* __restrict__ g, int n) {
    __shared__ __attribute__((aligned(16))) ushortT Xl[64][104];
    __shared__ __attribute__((aligned(16))) ushortT Wtl[96][104];
    const int tid = threadIdx.x;
    const int wave = tid >> 6, lane = tid & 63;
    const int quad = lane >> 4, m = lane & 15;
    const int row_base = blockIdx.x * 64;
    for (int i = tid; i < 96 * 24; i += 256) {
        int r = i / 24, c4 = (i % 24) * 4;
        *(ushort4*)&Wtl[r][c4] = *(const ushort4*)&Wt[r * 96 + c4];
    }
    for (int i = tid; i < 64 * 24; i += 256) {
        int r = i / 24, c4 = (i % 24) * 4;
        int grow = min(row_base + r, n - 1);
        if constexpr (sizeof(TIN) == 4) {
            float4 v = *(const float4*)&X[(size_t)grow * 96 + c4];
            ushort4 o = {f2b(v.x), f2b(v.y), f2b(v.z), f2b(v.w)};
            *(ushort4*)&Xl[r][c4] = o;
        } else {
            *(ushort4*)&Xl[r][c4] = *(const ushort4*)&X[(size_t)grow * 96 + c4];
        }
    }
    __syncthreads();
    f32x4 acc[6] = {};
#pragma unroll
    for (int ks = 0; ks < 3; ++ks) {
        bf16x8 a = *(bf16x8*)&Xl[wave * 16 + m][ks * 32 + quad * 8];
#pragma unroll
        for (int ct = 0; ct < 6; ++ct) {
            bf16x8 b = *(bf16x8*)&Wtl[ct * 16 + m][ks * 32 + quad * 8];
            acc[ct] = __builtin_amdgcn_mfma_f32_16x16x32_bf16(a, b, acc[ct], 0, 0, 0);
        }
    }
    float di[4];
    int rows[4];
#pragma unroll
    for (int r = 0; r < 4; ++r) {
        rows[r] = row_base + wave * 16 + quad * 4 + r;
        di[r] = (rows[r] < n) ? dinv[rows[r]] : 0.f;
    }
#pragma unroll
    for (int ct = 0; ct < 6; ++ct) {
        int colx = ct * 16 + m;
#pragma unroll
        for (int r = 0; r < 4; ++r)
            if (rows[r] < n) g[(size_t)rows[r] * 96 + colx] = f2b(acc[ct][r] * di[r]);
    }
}

// ---- MFMA GEMM [n,480]x[480,64] -> g(bf16). K = 5 JK segs x 96. ------------
// TIN=ushortT: segments are bf16 (hball); TIN=float: fp32 h (fallback).
template <typename TIN>
__global__ __launch_bounds__(256) void gemm_out_mfma(const TIN* __restrict__ hcat,
                                                     const ushortT* __restrict__ Wt, // [64][480]
                                                     const float* __restrict__ dinv,
                                                     ushortT* __restrict__ g, int n) {
    __shared__ __attribute__((aligned(16))) ushortT Xl[64][104];
    __shared__ __attribute__((aligned(16))) ushortT Wtl[64][104];
    const int tid = threadIdx.x;
    const int wave = tid >> 6, lane = tid & 63;
    const int quad = lane >> 4, m = lane & 15;
    const int row_base = blockIdx.x * 64;
    f32x4 acc[4] = {};
    for (int seg = 0; seg < 5; ++seg) {
        const TIN* hl = hcat + (size_t)seg * (size_t)n * 96;
        __syncthreads();  // protect previous tile
        for (int i = tid; i < 64 * 24; i += 256) {
            int r = i / 24, c4 = (i % 24) * 4;
            *(ushort4*)&Wtl[r][c4] = *(const ushort4*)&Wt[r * 480 + seg * 96 + c4];
        }
        for (int i = tid; i < 64 * 24; i += 256) {
            int r = i / 24, c4 = (i % 24) * 4;
            int grow = min(row_base + r, n - 1);
            if constexpr (sizeof(TIN) == 4) {
                float4 v = *(const float4*)&hl[(size_t)grow * 96 + c4];
                ushort4 o = {f2b(v.x), f2b(v.y), f2b(v.z), f2b(v.w)};
                *(ushort4*)&Xl[r][c4] = o;
            } else {
                *(ushort4*)&Xl[r][c4] = *(const ushort4*)&hl[(size_t)grow * 96 + c4];
            }
        }
        __syncthreads();
#pragma unroll
        for (int ks = 0; ks < 3; ++ks) {
            bf16x8 a = *(bf16x8*)&Xl[wave * 16 + m][ks * 32 + quad * 8];
#pragma unroll
            for (int ct = 0; ct < 4; ++ct) {
                bf16x8 b = *(bf16x8*)&Wtl[ct * 16 + m][ks * 32 + quad * 8];
                acc[ct] = __builtin_amdgcn_mfma_f32_16x16x32_bf16(a, b, acc[ct], 0, 0, 0);
            }
        }
    }
    float di[4];
    int rows[4];
#pragma unroll
    for (int r = 0; r < 4; ++r) {
        rows[r] = row_base + wave * 16 + quad * 4 + r;
        di[r] = (rows[r] < n) ? dinv[rows[r]] : 0.f;
    }
#pragma unroll
    for (int ct = 0; ct < 4; ++ct) {
        int colx = ct * 16 + m;
#pragma unroll
        for (int r = 0; r < 4; ++r)
            if (rows[r] < n) g[(size_t)rows[r] * 64 + colx] = f2b(acc[ct][r] * di[r]);
    }
}

// ---- CSR gather-aggregate: dual-half wave, 4-deep gather pipeline ----------
// Each half (32 lanes, NV=F/4 active) owns edges of one parity; main loop keeps
// 4 gathers in flight (8/wave) with batched col loads and dual accumulators.
template <int F, bool RELU, bool WRITE_BF16>
__global__ void agg_csr(const int* __restrict__ row_start, const int* __restrict__ col,
                        const ushortT* __restrict__ g, const float* __restrict__ dinv,
                        const float* __restrict__ b, float* __restrict__ out,
                        ushortT* __restrict__ hb, int n) {
    constexpr int NV = F / 4;
    const int lane = threadIdx.x & 63;
    const int half = lane >> 5;
    const int l32 = lane & 31;
    const int v = blockIdx.x * (blockDim.x >> 6) + (threadIdx.x >> 6);
    if (v >= n) return;
    const int e0 = row_start[v];
    const int e1 = row_start[v + 1];
    const bool act = (l32 < NV);
    const size_t fo = (size_t)l32 * 4;
    float a0 = 0.f, a1 = 0.f, a2 = 0.f, a3 = 0.f;
    float s0 = 0.f, s1 = 0.f, s2 = 0.f, s3 = 0.f;
    if (half == 0 && act) {  // self loop
        ushort4 s = *(const ushort4*)&g[(size_t)v * F + fo];
        a0 = b2f(s.x); a1 = b2f(s.y); a2 = b2f(s.z); a3 = b2f(s.w);
    }
    int e = e0 + half;
    // 4 edges per iteration (this half's parity): e, e+2, e+4, e+6
    for (; e + 6 < e1; e += 8) {
        int c0 = col[e], c1 = col[e + 2], c2 = col[e + 4], c3 = col[e + 6];
        if (act) {
            ushort4 g0 = *(const ushort4*)&g[(size_t)c0 * F + fo];
            ushort4 g1 = *(const ushort4*)&g[(size_t)c1 * F + fo];
            ushort4 g2 = *(const ushort4*)&g[(size_t)c2 * F + fo];
            ushort4 g3 = *(const ushort4*)&g[(size_t)c3 * F + fo];
            a0 += b2f(g0.x) + b2f(g1.x); s0 += b2f(g2.x) + b2f(g3.x);
            a1 += b2f(g0.y) + b2f(g1.y); s1 += b2f(g2.y) + b2f(g3.y);
            a2 += b2f(g0.z) + b2f(g1.z); s2 += b2f(g2.z) + b2f(g3.z);
            a3 += b2f(g0.w) + b2f(g1.w); s3 += b2f(g2.w) + b2f(g3.w);
        }
    }
    // 2 edges
    for (; e + 2 < e1; e += 4) {
        int c0 = col[e], c1 = col[e + 2];
        if (act) {
            ushort4 g0 = *(const ushort4*)&g[(size_t)c0 * F + fo];
            ushort4 g1 = *(const ushort4*)&g[(size_t)c1 * F + fo];
            a0 += b2f(g0.x) + b2f(g1.x);
            a1 += b2f(g0.y) + b2f(g1.y);
            a2 += b2f(g0.z) + b2f(g1.z);
            a3 += b2f(g0.w) + b2f(g1.w);
        }
    }
    // tail (at most 1)
    for (; e < e1; e += 2) {
        int c = col[e];
        if (act) {
            ushort4 g0 = *(const ushort4*)&g[(size_t)c * F + fo];
            a0 += b2f(g0.x); a1 += b2f(g0.y); a2 += b2f(g0.z); a3 += b2f(g0.w);
        }
    }
    a0 += s0; a1 += s1; a2 += s2; a3 += s3;
    a0 += __shfl_xor(a0, 32);
    a1 += __shfl_xor(a1, 32);
    a2 += __shfl_xor(a2, 32);
    a3 += __shfl_xor(a3, 32);
    if (half == 0 && act) {
        const float di = dinv[v];
        const float4 bv = *(const float4*)&b[l32 * 4];
        float4 r;
        r.x = a0 * di + bv.x;
        r.y = a1 * di + bv.y;
        r.z = a2 * di + bv.z;
        r.w = a3 * di + bv.w;
        if (RELU) {
            r.x = fmaxf(r.x, 0.f); r.y = fmaxf(r.y, 0.f);
            r.z = fmaxf(r.z, 0.f); r.w = fmaxf(r.w, 0.f);
        }
        *(float4*)&out[(size_t)v * F + l32 * 4] = r;
        if (WRITE_BF16) {
            ushort4 o = {f2b(r.x), f2b(r.y), f2b(r.z), f2b(r.w)};
            *(ushort4*)&hb[(size_t)v * F + l32 * 4] = o;
        }
    }
}

extern "C" void kernel_launch(void* const* d_in, const int* in_sizes, int n_in,
                              void* d_out, int out_size, void* d_ws, size_t ws_size,
                              hipStream_t stream) {
    const float* x    = (const float*)d_in[0];
    const int*   ei   = (const int*)d_in[1];
    const float* W1   = (const float*)d_in[4];
    const float* b1   = (const float*)d_in[5];
    const float* Wsl  = (const float*)d_in[6];
    const float* bsl  = (const float*)d_in[7];
    const float* Wout = (const float*)d_in[8];
    const float* bout = (const float*)d_in[9];

    const int n = in_sizes[0] / 96;  // 50000
    const int E = in_sizes[1] / 2;   // 800000
    const int* src = ei;
    const int* dst = ei + E;

    // ws: degi[n] row_start[n+1] partials[256] col[E] (int) | dinv[n] (f32)
    //     | g[n*96] | hball[5*n*96 or n*96] | wt1 wts wto (bf16)
    char* p = (char*)d_ws;
    int*     degi      = (int*)p;              p += (size_t)n * 4;
    int*     row_start = (int*)p;              p += (size_t)(n + 1) * 4;
    int*     partials  = (int*)p;              p += 256 * 4;
    int*     col       = (int*)p;              p += (size_t)E * 4;
    float*   dinv      = (float*)p;            p += (size_t)n * 4;
    ushortT* g         = (ushortT*)p;          p += (size_t)n * 96 * 2;
    ushortT* hball     = (ushortT*)p;
    const size_t wbytes = (size_t)(5 * 9216 + 30720) * 2;
    const size_t fixed  = (size_t)(p - (char*)d_ws);
    const bool   big    = (fixed + (size_t)5 * n * 96 * 2 + wbytes) <= ws_size;
    const size_t hbsz   = big ? (size_t)5 * n * 96 : (size_t)n * 96;
    p += hbsz * 2;
    ushortT* wt1 = (ushortT*)p;
    ushortT* wts = wt1 + 5 * 9216 - 4 * 9216;  // wt1[9216] then wts[4*9216]
    wts = wt1 + 9216;
    ushortT* wto = wts + 4 * 9216;

    float* out  = (float*)d_out;          // [n,64]
    float* hseg = out + (size_t)n * 64;   // h1 base; 5 segments of n*96 fp32

    const int nthr = 256;
    const int gE   = (E + nthr - 1) / nthr;
    const int gAgg = (n + 3) / 4;
    const int gT64 = (n + 63) / 64;
    const int nb   = (n + 255) / 256;

    // fused prep: weights + degi zero (replaces 6 tw launches + memset)
    const int prep_items = 76800 + n;
    prep_kernel<<<(prep_items + 255) / 256, 256, 0, stream>>>(W1, Wsl, Wout, wt1, wts,
                                                              wto, degi, n);

    // CSR build
    count_kernel<<<gE, nthr, 0, stream>>>(dst, degi, E);
    scan1<<<nb, 256, 0, stream>>>(degi, row_start, partials, n);
    scan2<<<1, 256, 0, stream>>>(partials, nb);
    scan3<<<nb, 256, 0, stream>>>(degi, row_start, partials, dinv, n, E);
    fill_kernel<<<gE, nthr, 0, stream>>>(src, dst, row_start, degi, col, E);

    // layer 1: x(fp32) -> g -> h1 (+hb seg 0)
    ushortT* hb0 = hball;
    gemm96_mfma<float><<<gT64, 256, 0, stream>>>(x, wt1, dinv, g, n);
    agg_csr<96, true, true><<<gAgg, nthr, 0, stream>>>(row_start, col, g, dinv, b1,
                                                       hseg, hb0, n);

    // hidden layers 2..5: hb(bf16) -> g -> h_{l+1} (+hb seg l+1)
    for (int l = 0; l < 4; ++l) {
        float*   hnext = hseg + (size_t)(l + 1) * (size_t)n * 96;
        ushortT* hbin  = big ? (hball + (size_t)l * n * 96) : hball;
        ushortT* hbout = big ? (hball + (size_t)(l + 1) * n * 96) : hball;
        gemm96_mfma<ushortT><<<gT64, 256, 0, stream>>>(hbin, wts + (size_t)l * 9216,
                                                       dinv, g, n);
        agg_csr<96, true, true><<<gAgg, nthr, 0, stream>>>(row_start, col, g, dinv,
                                                           bsl + (size_t)l * 96, hnext,
                                                           hbout, n);
    }

    // output layer: JK concat -> out[n,64]
    if (big)
        gemm_out_mfma<ushortT><<<gT64, 256, 0, stream>>>(hball, wto, dinv, g, n);
    else
        gemm_out_mfma<float><<<gT64, 256, 0, stream>>>(hseg, wto, dinv, g, n);
    agg_csr<64, false, false><<<gAgg, nthr, 0, stream>>>(row_start, col, g, dinv, bout,
                                                         out, nullptr, n);
}

// Round 2
// 515.681 us; speedup vs baseline: 1.1085x; 1.0160x over previous
//
#include <hip/hip_runtime.h>

// JKNet (6-layer GCN + JK concat) on MI355X — R9:
//   * agg_csr rewrite: per-half lane-parallel col preload (one memory round for
//     up to 32 indices) + __shfl broadcast + 8-deep gather chunks. Removes the
//     serialized col->gather dependency per batch (was latency-bound).
//   * rest identical to R8 (fused prep, bf16 JK segments, MFMA GEMMs).
// Layout facts (learn_hip m89): A[m=lane&15][k=quad*8+j], B[k][n=lane&15] (k=quad*8+j),
// D: col=lane&15, row=quad*4+reg.

typedef unsigned short ushortT;
typedef __attribute__((ext_vector_type(8))) short bf16x8;
typedef __attribute__((ext_vector_type(4))) float f32x4;

__device__ __forceinline__ ushortT f2b(float f) {
    union { float f; unsigned int u; } v;
    v.f = f;
    unsigned int lsb = (v.u >> 16) & 1u;
    v.u += 0x7fffu + lsb;  // RNE
    return (ushortT)(v.u >> 16);
}
__device__ __forceinline__ float b2f(ushortT u) {
    union { float f; unsigned int u; } v;
    v.u = ((unsigned int)u) << 16;
    return v.f;
}

// ---- fused prep: transpose+convert all weights, zero degi -----------------
__global__ void prep_kernel(const float* __restrict__ W1, const float* __restrict__ Wsl,
                            const float* __restrict__ Wout, ushortT* __restrict__ wt1,
                            ushortT* __restrict__ wts, ushortT* __restrict__ wto,
                            int* __restrict__ degi, int n) {
    const int SQ = 96 * 96;        // 9216
    const int T1 = 5 * SQ;         // 46080
    const int T2 = T1 + 480 * 64;  // 76800
    int i = blockIdx.x * blockDim.x + threadIdx.x;
    if (i < T1) {
        int l = i / SQ, j = i - l * SQ;
        int c = j / 96, k = j - c * 96;
        if (l == 0)
            wt1[j] = f2b(W1[k * 96 + c]);
        else
            wts[(size_t)(l - 1) * SQ + j] = f2b(Wsl[(size_t)(l - 1) * SQ + k * 96 + c]);
    } else if (i < T2) {
        int j = i - T1;
        int c = j / 480, k = j - c * 480;
        wto[j] = f2b(Wout[(size_t)k * 64 + c]);
    } else {
        int j = i - T2;
        if (j < n) degi[j] = 0;
    }
}

// ---- CSR build -------------------------------------------------------------
__global__ void count_kernel(const int* __restrict__ dst, int* __restrict__ degi, int E) {
    int e = blockIdx.x * blockDim.x + threadIdx.x;
    if (e < E) atomicAdd(&degi[dst[e]], 1);
}

__global__ void scan1(const int* __restrict__ degi, int* __restrict__ row_start,
                      int* __restrict__ partials, int n) {
    __shared__ int tmp[256];
    const int t = threadIdx.x;
    const int i = blockIdx.x * 256 + t;
    int val = (i < n) ? degi[i] : 0;
    tmp[t] = val;
    __syncthreads();
    for (int off = 1; off < 256; off <<= 1) {
        int v = (t >= off) ? tmp[t - off] : 0;
        __syncthreads();
        tmp[t] += v;
        __syncthreads();
    }
    if (i < n) row_start[i] = tmp[t] - val;
    if (t == 255) partials[blockIdx.x] = tmp[255];
}

__global__ void scan2(int* __restrict__ partials, int nb) {
    __shared__ int tmp[256];
    const int t = threadIdx.x;
    int val = (t < nb) ? partials[t] : 0;
    tmp[t] = val;
    __syncthreads();
    for (int off = 1; off < 256; off <<= 1) {
        int v = (t >= off) ? tmp[t - off] : 0;
        __syncthreads();
        tmp[t] += v;
        __syncthreads();
    }
    if (t < nb) partials[t] = tmp[t] - val;
}

__global__ void scan3(const int* __restrict__ degi, int* __restrict__ row_start,
                      const int* __restrict__ partials, float* __restrict__ dinv,
                      int n, int E) {
    const int i = blockIdx.x * 256 + threadIdx.x;
    if (i < n) {
        row_start[i] += partials[blockIdx.x];
        dinv[i] = rsqrtf((float)degi[i] + 1.0f);
    }
    if (i == 0) row_start[n] = E;
}

__global__ void fill_kernel(const int* __restrict__ src, const int* __restrict__ dst,
                            const int* __restrict__ row_start, int* __restrict__ degi,
                            int* __restrict__ col, int E) {
    int e = blockIdx.x * blockDim.x + threadIdx.x;
    if (e < E) {
        int d = dst[e];
        int pos = row_start[d] + atomicSub(&degi[d], 1) - 1;
        col[pos] = src[e];
    }
}

// ---- MFMA GEMM [n,96]x[96,96] -> g(bf16) = (X@W)*dinv[row] -----------------
template <typename TIN>
__global__ __launch_bounds__(256) void gemm96_mfma(const TIN* __restrict__ X,
                                                   const ushortT* __restrict__ Wt, // [96][96] c-major
                                                   const float* __restrict__ dinv,
                                                   ushortT* __restrict__ g, int n) {
    __shared__ __attribute__((aligned(16))) ushortT Xl[64][104];
    __shared__ __attribute__((aligned(16))) ushortT Wtl[96][104];
    const int tid = threadIdx.x;
    const int wave = tid >> 6, lane = tid & 63;
    const int quad = lane >> 4, m = lane & 15;
    const int row_base = blockIdx.x * 64;
    for (int i = tid; i < 96 * 24; i += 256) {
        int r = i / 24, c4 = (i % 24) * 4;
        *(ushort4*)&Wtl[r][c4] = *(const ushort4*)&Wt[r * 96 + c4];
    }
    for (int i = tid; i < 64 * 24; i += 256) {
        int r = i / 24, c4 = (i % 24) * 4;
        int grow = min(row_base + r, n - 1);
        if constexpr (sizeof(TIN) == 4) {
            float4 v = *(const float4*)&X[(size_t)grow * 96 + c4];
            ushort4 o = {f2b(v.x), f2b(v.y), f2b(v.z), f2b(v.w)};
            *(ushort4*)&Xl[r][c4] = o;
        } else {
            *(ushort4*)&Xl[r][c4] = *(const ushort4*)&X[(size_t)grow * 96 + c4];
        }
    }
    __syncthreads();
    f32x4 acc[6] = {};
#pragma unroll
    for (int ks = 0; ks < 3; ++ks) {
        bf16x8 a = *(bf16x8*)&Xl[wave * 16 + m][ks * 32 + quad * 8];
#pragma unroll
        for (int ct = 0; ct < 6; ++ct) {
            bf16x8 b = *(bf16x8*)&Wtl[ct * 16 + m][ks * 32 + quad * 8];
            acc[ct] = __builtin_amdgcn_mfma_f32_16x16x32_bf16(a, b, acc[ct], 0, 0, 0);
        }
    }
    float di[4];
    int rows[4];
#pragma unroll
    for (int r = 0; r < 4; ++r) {
        rows[r] = row_base + wave * 16 + quad * 4 + r;
        di[r] = (rows[r] < n) ? dinv[rows[r]] : 0.f;
    }
#pragma unroll
    for (int ct = 0; ct < 6; ++ct) {
        int colx = ct * 16 + m;
#pragma unroll
        for (int r = 0; r < 4; ++r)
            if (rows[r] < n) g[(size_t)rows[r] * 96 + colx] = f2b(acc[ct][r] * di[r]);
    }
}

// ---- MFMA GEMM [n,480]x[480,64] -> g(bf16). K = 5 JK segs x 96. ------------
template <typename TIN>
__global__ __launch_bounds__(256) void gemm_out_mfma(const TIN* __restrict__ hcat,
                                                     const ushortT* __restrict__ Wt, // [64][480]
                                                     const float* __restrict__ dinv,
                                                     ushortT* __restrict__ g, int n) {
    __shared__ __attribute__((aligned(16))) ushortT Xl[64][104];
    __shared__ __attribute__((aligned(16))) ushortT Wtl[64][104];
    const int tid = threadIdx.x;
    const int wave = tid >> 6, lane = tid & 63;
    const int quad = lane >> 4, m = lane & 15;
    const int row_base = blockIdx.x * 64;
    f32x4 acc[4] = {};
    for (int seg = 0; seg < 5; ++seg) {
        const TIN* hl = hcat + (size_t)seg * (size_t)n * 96;
        __syncthreads();  // protect previous tile
        for (int i = tid; i < 64 * 24; i += 256) {
            int r = i / 24, c4 = (i % 24) * 4;
            *(ushort4*)&Wtl[r][c4] = *(const ushort4*)&Wt[r * 480 + seg * 96 + c4];
        }
        for (int i = tid; i < 64 * 24; i += 256) {
            int r = i / 24, c4 = (i % 24) * 4;
            int grow = min(row_base + r, n - 1);
            if constexpr (sizeof(TIN) == 4) {
                float4 v = *(const float4*)&hl[(size_t)grow * 96 + c4];
                ushort4 o = {f2b(v.x), f2b(v.y), f2b(v.z), f2b(v.w)};
                *(ushort4*)&Xl[r][c4] = o;
            } else {
                *(ushort4*)&Xl[r][c4] = *(const ushort4*)&hl[(size_t)grow * 96 + c4];
            }
        }
        __syncthreads();
#pragma unroll
        for (int ks = 0; ks < 3; ++ks) {
            bf16x8 a = *(bf16x8*)&Xl[wave * 16 + m][ks * 32 + quad * 8];
#pragma unroll
            for (int ct = 0; ct < 4; ++ct) {
                bf16x8 b = *(bf16x8*)&Wtl[ct * 16 + m][ks * 32 + quad * 8];
                acc[ct] = __builtin_amdgcn_mfma_f32_16x16x32_bf16(a, b, acc[ct], 0, 0, 0);
            }
        }
    }
    float di[4];
    int rows[4];
#pragma unroll
    for (int r = 0; r < 4; ++r) {
        rows[r] = row_base + wave * 16 + quad * 4 + r;
        di[r] = (rows[r] < n) ? dinv[rows[r]] : 0.f;
    }
#pragma unroll
    for (int ct = 0; ct < 4; ++ct) {
        int colx = ct * 16 + m;
#pragma unroll
        for (int r = 0; r < 4; ++r)
            if (rows[r] < n) g[(size_t)rows[r] * 64 + colx] = f2b(acc[ct][r] * di[r]);
    }
}

// ---- CSR gather-aggregate: col preload + shfl broadcast + 8-deep gathers ---
// One wave per row; halves own edge parities. Each half lane-parallel-loads up
// to 32 col indices in ONE memory round, broadcasts via __shfl (intra-half:
// kc is uniform within a half so exec-divergence between halves is safe),
// then issues gathers in 8-deep chunks (16 in flight per wave).
template <int F, bool RELU, bool WRITE_BF16>
__global__ void agg_csr(const int* __restrict__ row_start, const int* __restrict__ col,
                        const ushortT* __restrict__ g, const float* __restrict__ dinv,
                        const float* __restrict__ b, float* __restrict__ out,
                        ushortT* __restrict__ hb, int n) {
    constexpr int NV = F / 4;
    const int lane = threadIdx.x & 63;
    const int half = lane >> 5;
    const int l32 = lane & 31;
    const int v = blockIdx.x * (blockDim.x >> 6) + (threadIdx.x >> 6);
    if (v >= n) return;
    const int e0 = row_start[v];
    const int e1 = row_start[v + 1];
    const bool act = (l32 < NV);
    const size_t fo = (size_t)l32 * 4;
    float a0 = 0.f, a1 = 0.f, a2 = 0.f, a3 = 0.f;
    float s0 = 0.f, s1 = 0.f, s2 = 0.f, s3 = 0.f;
    if (half == 0 && act) {  // self loop
        ushort4 s = *(const ushort4*)&g[(size_t)v * F + fo];
        a0 = b2f(s.x); a1 = b2f(s.y); a2 = b2f(s.z); a3 = b2f(s.w);
    }
    const int total = e1 - e0;
    const int cntH = (total - half + 1) >> 1;  // this half's parity edge count
    const int base = e0 + half;
    const int sb = half << 5;
    int done = 0;
    while (done < cntH) {
        const int kc = min(cntH - done, 32);
        int cv = 0;
        if (l32 < kc) cv = col[base + 2 * (done + l32)];
        int j = 0;
        for (; j + 8 <= kc; j += 8) {
            int c0 = __shfl(cv, sb + j + 0);
            int c1 = __shfl(cv, sb + j + 1);
            int c2 = __shfl(cv, sb + j + 2);
            int c3 = __shfl(cv, sb + j + 3);
            int c4 = __shfl(cv, sb + j + 4);
            int c5 = __shfl(cv, sb + j + 5);
            int c6 = __shfl(cv, sb + j + 6);
            int c7 = __shfl(cv, sb + j + 7);
            if (act) {
                ushort4 g0 = *(const ushort4*)&g[(size_t)c0 * F + fo];
                ushort4 g1 = *(const ushort4*)&g[(size_t)c1 * F + fo];
                ushort4 g2 = *(const ushort4*)&g[(size_t)c2 * F + fo];
                ushort4 g3 = *(const ushort4*)&g[(size_t)c3 * F + fo];
                ushort4 g4 = *(const ushort4*)&g[(size_t)c4 * F + fo];
                ushort4 g5 = *(const ushort4*)&g[(size_t)c5 * F + fo];
                ushort4 g6 = *(const ushort4*)&g[(size_t)c6 * F + fo];
                ushort4 g7 = *(const ushort4*)&g[(size_t)c7 * F + fo];
                a0 += (b2f(g0.x) + b2f(g1.x)) + (b2f(g2.x) + b2f(g3.x));
                a1 += (b2f(g0.y) + b2f(g1.y)) + (b2f(g2.y) + b2f(g3.y));
                a2 += (b2f(g0.z) + b2f(g1.z)) + (b2f(g2.z) + b2f(g3.z));
                a3 += (b2f(g0.w) + b2f(g1.w)) + (b2f(g2.w) + b2f(g3.w));
                s0 += (b2f(g4.x) + b2f(g5.x)) + (b2f(g6.x) + b2f(g7.x));
                s1 += (b2f(g4.y) + b2f(g5.y)) + (b2f(g6.y) + b2f(g7.y));
                s2 += (b2f(g4.z) + b2f(g5.z)) + (b2f(g6.z) + b2f(g7.z));
                s3 += (b2f(g4.w) + b2f(g5.w)) + (b2f(g6.w) + b2f(g7.w));
            }
        }
        if (j + 4 <= kc) {
            int c0 = __shfl(cv, sb + j + 0);
            int c1 = __shfl(cv, sb + j + 1);
            int c2 = __shfl(cv, sb + j + 2);
            int c3 = __shfl(cv, sb + j + 3);
            if (act) {
                ushort4 g0 = *(const ushort4*)&g[(size_t)c0 * F + fo];
                ushort4 g1 = *(const ushort4*)&g[(size_t)c1 * F + fo];
                ushort4 g2 = *(const ushort4*)&g[(size_t)c2 * F + fo];
                ushort4 g3 = *(const ushort4*)&g[(size_t)c3 * F + fo];
                a0 += b2f(g0.x) + b2f(g1.x);
                a1 += b2f(g0.y) + b2f(g1.y);
                a2 += b2f(g0.z) + b2f(g1.z);
                a3 += b2f(g0.w) + b2f(g1.w);
                s0 += b2f(g2.x) + b2f(g3.x);
                s1 += b2f(g2.y) + b2f(g3.y);
                s2 += b2f(g2.z) + b2f(g3.z);
                s3 += b2f(g2.w) + b2f(g3.w);
            }
            j += 4;
        }
        if (j + 2 <= kc) {
            int c0 = __shfl(cv, sb + j + 0);
            int c1 = __shfl(cv, sb + j + 1);
            if (act) {
                ushort4 g0 = *(const ushort4*)&g[(size_t)c0 * F + fo];
                ushort4 g1 = *(const ushort4*)&g[(size_t)c1 * F + fo];
                a0 += b2f(g0.x) + b2f(g1.x);
                a1 += b2f(g0.y) + b2f(g1.y);
                a2 += b2f(g0.z) + b2f(g1.z);
                a3 += b2f(g0.w) + b2f(g1.w);
            }
            j += 2;
        }
        if (j < kc) {
            int c0 = __shfl(cv, sb + j);
            if (act) {
                ushort4 g0 = *(const ushort4*)&g[(size_t)c0 * F + fo];
                a0 += b2f(g0.x); a1 += b2f(g0.y); a2 += b2f(g0.z); a3 += b2f(g0.w);
            }
        }
        done += kc;
    }
    a0 += s0; a1 += s1; a2 += s2; a3 += s3;
    a0 += __shfl_xor(a0, 32);
    a1 += __shfl_xor(a1, 32);
    a2 += __shfl_xor(a2, 32);
    a3 += __shfl_xor(a3, 32);
    if (half == 0 && act) {
        const float di = dinv[v];
        const float4 bv = *(const float4*)&b[l32 * 4];
        float4 r;
        r.x = a0 * di + bv.x;
        r.y = a1 * di + bv.y;
        r.z = a2 * di + bv.z;
        r.w = a3 * di + bv.w;
        if (RELU) {
            r.x = fmaxf(r.x, 0.f); r.y = fmaxf(r.y, 0.f);
            r.z = fmaxf(r.z, 0.f); r.w = fmaxf(r.w, 0.f);
        }
        *(float4*)&out[(size_t)v * F + l32 * 4] = r;
        if (WRITE_BF16) {
            ushort4 o = {f2b(r.x), f2b(r.y), f2b(r.z), f2b(r.w)};
            *(ushort4*)&hb[(size_t)v * F + l32 * 4] = o;
        }
    }
}

extern "C" void kernel_launch(void* const* d_in, const int* in_sizes, int n_in,
                              void* d_out, int out_size, void* d_ws, size_t ws_size,
                              hipStream_t stream) {
    const float* x    = (const float*)d_in[0];
    const int*   ei   = (const int*)d_in[1];
    const float* W1   = (const float*)d_in[4];
    const float* b1   = (const float*)d_in[5];
    const float* Wsl  = (const float*)d_in[6];
    const float* bsl  = (const float*)d_in[7];
    const float* Wout = (const float*)d_in[8];
    const float* bout = (const float*)d_in[9];

    const int n = in_sizes[0] / 96;  // 50000
    const int E = in_sizes[1] / 2;   // 800000
    const int* src = ei;
    const int* dst = ei + E;

    char* p = (char*)d_ws;
    int*     degi      = (int*)p;              p += (size_t)n * 4;
    int*     row_start = (int*)p;              p += (size_t)(n + 1) * 4;
    int*     partials  = (int*)p;              p += 256 * 4;
    int*     col       = (int*)p;              p += (size_t)E * 4;
    float*   dinv      = (float*)p;            p += (size_t)n * 4;
    ushortT* g         = (ushortT*)p;          p += (size_t)n * 96 * 2;
    ushortT* hball     = (ushortT*)p;
    const size_t wbytes = (size_t)(5 * 9216 + 30720) * 2;
    const size_t fixed  = (size_t)(p - (char*)d_ws);
    const bool   big    = (fixed + (size_t)5 * n * 96 * 2 + wbytes) <= ws_size;
    const size_t hbsz   = big ? (size_t)5 * n * 96 : (size_t)n * 96;
    p += hbsz * 2;
    ushortT* wt1 = (ushortT*)p;
    ushortT* wts = wt1 + 9216;
    ushortT* wto = wts + 4 * 9216;

    float* out  = (float*)d_out;          // [n,64]
    float* hseg = out + (size_t)n * 64;   // h1 base; 5 segments of n*96 fp32

    const int nthr = 256;
    const int gE   = (E + nthr - 1) / nthr;
    const int gAgg = (n + 3) / 4;
    const int gT64 = (n + 63) / 64;
    const int nb   = (n + 255) / 256;

    // fused prep: weights + degi zero
    const int prep_items = 76800 + n;
    prep_kernel<<<(prep_items + 255) / 256, 256, 0, stream>>>(W1, Wsl, Wout, wt1, wts,
                                                              wto, degi, n);

    // CSR build
    count_kernel<<<gE, nthr, 0, stream>>>(dst, degi, E);
    scan1<<<nb, 256, 0, stream>>>(degi, row_start, partials, n);
    scan2<<<1, 256, 0, stream>>>(partials, nb);
    scan3<<<nb, 256, 0, stream>>>(degi, row_start, partials, dinv, n, E);
    fill_kernel<<<gE, nthr, 0, stream>>>(src, dst, row_start, degi, col, E);

    // layer 1: x(fp32) -> g -> h1 (+hb seg 0)
    ushortT* hb0 = hball;
    gemm96_mfma<float><<<gT64, 256, 0, stream>>>(x, wt1, dinv, g, n);
    agg_csr<96, true, true><<<gAgg, nthr, 0, stream>>>(row_start, col, g, dinv, b1,
                                                       hseg, hb0, n);

    // hidden layers 2..5: hb(bf16) -> g -> h_{l+1} (+hb seg l+1)
    for (int l = 0; l < 4; ++l) {
        float*   hnext = hseg + (size_t)(l + 1) * (size_t)n * 96;
        ushortT* hbin  = big ? (hball + (size_t)l * n * 96) : hball;
        ushortT* hbout = big ? (hball + (size_t)(l + 1) * n * 96) : hball;
        gemm96_mfma<ushortT><<<gT64, 256, 0, stream>>>(hbin, wts + (size_t)l * 9216,
                                                       dinv, g, n);
        agg_csr<96, true, true><<<gAgg, nthr, 0, stream>>>(row_start, col, g, dinv,
                                                           bsl + (size_t)l * 96, hnext,
                                                           hbout, n);
    }

    // output layer: JK concat -> out[n,64]
    if (big)
        gemm_out_mfma<ushortT><<<gT64, 256, 0, stream>>>(hball, wto, dinv, g, n);
    else
        gemm_out_mfma<float><<<gT64, 256, 0, stream>>>(hseg, wto, dinv, g, n);
    agg_csr<64, false, false><<<gAgg, nthr, 0, stream>>>(row_start, col, g, dinv, bout,
                                                         out, nullptr, n);
}